// Round 5
// baseline (266.832 us; speedup 1.0000x reference)
//
#include <hip/hip_runtime.h>
#include <math.h>

// RWKV single-token forward — ONE persistent kernel, continuous weight stream.
// Round-5 changes:
//  - Weight loads for phase k+1 issued at the TOP of phase k's compute (plus a
//    second tranche after the arrive flag), so the memory pipe is busy through
//    compute + barrier, not just the arrive->wait window.
//  - lds_sync(): lgkmcnt-only barrier (raw s_barrier + sched_barrier pins)
//    replaces __syncthreads inside phases, so in-flight weight prefetches are
//    NOT drained by vmcnt(0) at every LDS handoff. Real __syncthreads remains
//    only at bar_arrive (needed to drain coherent result stores).
//  - Cross-block data loads via 8B relaxed agent atomics (precise compiler
//    waitcnt, no blanket vmcnt(0)).
//  - Elementwise per-layer vectors (ln w/b, mix vectors, tf/td/sb/sc)
//    prefetched one phase ahead into registers.

constexpr int E = 1024;
constexpr int H = 4096;
constexpr int V = 50277;
constexpr int L = 12;
constexpr int NBLK = 256;
constexpr int NTHR = 512;
constexpr float LN_EPS = 9.999999747378752e-06f;

#define SCOPE_AGENT __HIP_MEMORY_SCOPE_AGENT

__device__ __forceinline__ void cstoref(float *p, float v) {
  __hip_atomic_store(p, v, __ATOMIC_RELAXED, SCOPE_AGENT);
}
__device__ __forceinline__ void cstoreu(unsigned *p, unsigned v) {
  __hip_atomic_store(p, v, __ATOMIC_RELAXED, SCOPE_AGENT);
}
__device__ __forceinline__ unsigned cloadu(const unsigned *p) {
  return __hip_atomic_load(p, __ATOMIC_RELAXED, SCOPE_AGENT);
}
__device__ __forceinline__ float2 cload2(const float *p) {
  union { unsigned long long u; float2 f; } c;
  c.u = __hip_atomic_load((const unsigned long long *)p, __ATOMIC_RELAXED, SCOPE_AGENT);
  return c.f;
}

// Workgroup barrier WITHOUT vmem drain: orders LDS only. Keeps weight
// prefetches in flight across intra-phase sync points.
__device__ __forceinline__ void lds_sync() {
  __builtin_amdgcn_sched_barrier(0);
  asm volatile("s_waitcnt lgkmcnt(0)" ::: "memory");
  __builtin_amdgcn_s_barrier();
  __builtin_amdgcn_sched_barrier(0);
}

struct Args {
  const float *statea, *stateb, *statec, *stated, *pre;
  const float *ln1w, *ln1b, *ln2w, *ln2b;
  const float *ak, *ar, *av, *kk, *vv, *rr, *tf, *td, *ovv;
  const float *tmk, *tmr, *kf, *rf, *vf;
  const float *post0, *post1, *post2;
  const int *token;
  float *out;
  float *ws;        // coherent scratch: u[1024], sxx[1024], x[1024], km[4096]
  unsigned *flags;  // per-block arrival flags, stride 32 dwords (128 B)
};

// Arrive: __syncthreads drains each wave's coherent result stores (vmcnt) and
// LDS ops, then one flag store.
__device__ __forceinline__ void bar_arrive(const Args &a, unsigned ep, int blk) {
  __syncthreads();
  if (threadIdx.x == 0) cstoreu(&a.flags[blk * 32], ep);
  __builtin_amdgcn_sched_barrier(0);
}

// Spin: tid<256 each poll one block's flag; raw s_barrier releases the block
// (no vmem drain -> tranche-2 prefetches stay in flight into the next phase).
__device__ __forceinline__ void bar_spin(const Args &a, unsigned ep) {
  __builtin_amdgcn_sched_barrier(0);
  if (threadIdx.x < NBLK) {
    while (cloadu(&a.flags[threadIdx.x * 32]) < ep)
      __builtin_amdgcn_s_sleep(2);
  }
  __builtin_amdgcn_s_barrier();
  __builtin_amdgcn_sched_barrier(0);
}

__device__ __forceinline__ float wred(float v) {
#pragma unroll
  for (int off = 32; off; off >>= 1) v += __shfl_down(v, off, 64);
  return v;
}

__device__ __forceinline__ float dot4(float4 w, float4 x) {
  return w.x * x.x + w.y * x.y + w.z * x.z + w.w * x.w;
}

// Stage v (elements 2tid,2tid+1) into s_x, return (mean, rstd). LDS-only sync.
__device__ __forceinline__ float2 block_stats_v(float2 v, float *s_x, float *s_red,
                                                int tid, int lane, int wid) {
  reinterpret_cast<float2 *>(s_x)[tid] = v;
  float s = v.x + v.y, s2 = v.x * v.x + v.y * v.y;
#pragma unroll
  for (int off = 32; off; off >>= 1) {
    s += __shfl_down(s, off, 64);
    s2 += __shfl_down(s2, off, 64);
  }
  if (lane == 0) { s_red[wid] = s; s_red[8 + wid] = s2; }
  lds_sync();
  float ts = 0.f, ts2 = 0.f;
#pragma unroll
  for (int i = 0; i < 8; ++i) { ts += s_red[i]; ts2 += s_red[8 + i]; }
  float m = ts * (1.0f / E);
  float var = ts2 * (1.0f / E) - m * m;
  return make_float2(m, rsqrtf(var + LN_EPS));
}

__device__ __forceinline__ void loadrow(float4 *d, const float4 *P, int r, int lane) {
  const float4 *p = P + (size_t)r * 256;
  d[0] = p[lane]; d[1] = p[lane + 64]; d[2] = p[lane + 128]; d[3] = p[lane + 192];
}

__global__ __launch_bounds__(NTHR) void rwkv_fused(Args a) {
  __shared__ __align__(16) float s_a[4096];
  __shared__ __align__(16) float s_x[1024];
  __shared__ __align__(16) float s_y[1024];
  __shared__ float s_pp[24];
  __shared__ float s_red[16];
  __shared__ float s_rt[4];

  const int tid = threadIdx.x;
  const int lane = tid & 63;
  const int wid = tid >> 6;        // 0..7
  const int blk = blockIdx.x;
  const int rloc = wid >> 1;       // 0..3
  const int h = wid & 1;           // half of the row this wave owns
  const int grow = blk * 4 + rloc; // global E-row 0..1023
  const int b0h = h * 128 + lane;  // half-row float4 base
  const int bv = h * 512 + lane;   // vf half-row float4 base

  float *ws_u = a.ws, *ws_sxx = a.ws + 1024, *ws_x = a.ws + 2048, *ws_km = a.ws + 3072;
  float *out_logits = a.out;
  float *out_aaa = a.out + V;
  float *out_bbb = out_aaa + L * E;
  float *out_ccc = out_bbb + L * E;
  float *out_ddd = out_ccc + L * E;

  const int tok = a.token[0];
  const float *pre_row = a.pre + (size_t)tok * E;
  const float4 *s4a = reinterpret_cast<const float4 *>(s_a);

  unsigned ep = 1;

  // Loop-carried P1 prefetch state (layer l's P1 weights/vectors).
  float4 pw1[6];
  float2 e1w, e1b, e1sa, e1kk, e1vv, e1rr;
  float e_tf = 0.f, e_td = 0.f, e_sb = 0.f, e_sc = 0.f;

  // Prologue: layer-0 P1 prefetch.
  {
    const float4 *kr = reinterpret_cast<const float4 *>(a.ak + (size_t)grow * E);
    const float4 *vr = reinterpret_cast<const float4 *>(a.av + (size_t)grow * E);
    const float4 *rr4 = reinterpret_cast<const float4 *>(a.ar + (size_t)grow * E);
    pw1[0] = kr[b0h]; pw1[1] = kr[b0h + 64];
    pw1[2] = vr[b0h]; pw1[3] = vr[b0h + 64];
    pw1[4] = rr4[b0h]; pw1[5] = rr4[b0h + 64];
    e1w = reinterpret_cast<const float2 *>(a.ln1w)[tid];
    e1b = reinterpret_cast<const float2 *>(a.ln1b)[tid];
    e1sa = reinterpret_cast<const float2 *>(a.statea)[tid];
    e1kk = reinterpret_cast<const float2 *>(a.kk)[tid];
    e1vv = reinterpret_cast<const float2 *>(a.vv)[tid];
    e1rr = reinterpret_cast<const float2 *>(a.rr)[tid];
    if (tid < 4) {
      size_t o = (size_t)blk * 4 + tid;
      e_tf = a.tf[o]; e_td = a.td[o]; e_sb = a.stateb[o]; e_sc = a.statec[o];
    }
  }

#pragma unroll 1
  for (int l = 0; l < L; ++l) {
    const size_t lE = (size_t)l * E;
    float4 pw2[2], pw3[10], pw4[8];
    float2 e3w, e3b, e3sd, e3tk, e3tr;

    // ================= P1: LN1 + k/v/r matvecs + wkv =================
    {
      float2 v;
      if (l == 0) v = reinterpret_cast<const float2 *>(pre_row)[tid];
      else        v = cload2(ws_x + 2 * tid);
      // t1 prefetch: P2 (ovv) + first kf row of P3
      {
        const float4 *orow = reinterpret_cast<const float4 *>(a.ovv + (lE + grow) * E);
        pw2[0] = orow[b0h]; pw2[1] = orow[b0h + 64];
        const float *kfb = a.kf + (size_t)l * H * E;
        const float4 *k0 = reinterpret_cast<const float4 *>(kfb + (size_t)(blk * 16 + wid) * E);
        pw3[0] = k0[lane];       pw3[1] = k0[lane + 64];
        pw3[2] = k0[lane + 128]; pw3[3] = k0[lane + 192];
      }
      float2 st = block_stats_v(v, s_x, s_red, tid, lane, wid);
      float2 xy = make_float2((v.x - st.x) * st.y * e1w.x + e1b.x,
                              (v.y - st.x) * st.y * e1w.y + e1b.y);
      reinterpret_cast<float2 *>(s_y)[tid] = xy;
      reinterpret_cast<float2 *>(s_a)[tid] =
          make_float2(xy.x + e1kk.x * e1sa.x, xy.y + e1kk.y * e1sa.y);
      reinterpret_cast<float2 *>(s_a + 1024)[tid] =
          make_float2(xy.x + e1vv.x * e1sa.x, xy.y + e1vv.y * e1sa.y);
      reinterpret_cast<float2 *>(s_a + 2048)[tid] =
          make_float2(xy.x + e1rr.x * e1sa.x, xy.y + e1rr.y * e1sa.y);
      lds_sync();
      float accK = dot4(pw1[0], s4a[b0h]) + dot4(pw1[1], s4a[b0h + 64]);
      float accV = dot4(pw1[2], s4a[256 + b0h]) + dot4(pw1[3], s4a[256 + b0h + 64]);
      float accR = dot4(pw1[4], s4a[512 + b0h]) + dot4(pw1[5], s4a[512 + b0h + 64]);
      accK = wred(accK); accV = wred(accV); accR = wred(accR);
      if (lane == 0) {
        s_pp[wid * 3 + 0] = accK;
        s_pp[wid * 3 + 1] = accV;
        s_pp[wid * 3 + 2] = accR;
      }
      lds_sync();
      if (tid < 4) {
        size_t o = lE + blk * 4 + tid;
        float K = s_pp[(2 * tid) * 3] + s_pp[(2 * tid + 1) * 3];
        float Vv = s_pp[(2 * tid) * 3 + 1] + s_pp[(2 * tid + 1) * 3 + 1];
        float R = s_pp[(2 * tid) * 3 + 2] + s_pp[(2 * tid + 1) * 3 + 2];
        float kx = expf(K), rx = expf(R) + 1.0f;
        float etf = expf(e_tf), etd = expf(e_td);
        float w_ = e_sb + etf * kx * Vv;
        float d_ = e_sc * rx + etf * kx * rx;
        cstoref(&ws_u[blk * 4 + tid], w_ / (d_ + 0.001f));
        out_bbb[o] = e_sb * etd + kx * Vv;
        out_ccc[o] = e_sc * etd + kx;
        out_aaa[o] = s_y[blk * 4 + tid];
      }
    }
    bar_arrive(a, ep, blk);
    { // t2: second kf row of P3
      const float *kfb = a.kf + (size_t)l * H * E;
      const float4 *k1 = reinterpret_cast<const float4 *>(kfb + (size_t)(blk * 16 + 8 + wid) * E);
      pw3[4] = k1[lane];       pw3[5] = k1[lane + 64];
      pw3[6] = k1[lane + 128]; pw3[7] = k1[lane + 192];
    }
    bar_spin(a, ep); ++ep;

    // ================= P2: sxx = x + ovv @ u =================
    {
      float2 u2 = cload2(ws_u + 2 * tid);
      // t1: rf + P3 elementwise + first half of vf (P4)
      {
        const float4 *rrow = reinterpret_cast<const float4 *>(a.rf + (lE + grow) * E);
        pw3[8] = rrow[b0h]; pw3[9] = rrow[b0h + 64];
        e3w = reinterpret_cast<const float2 *>(a.ln2w + lE)[tid];
        e3b = reinterpret_cast<const float2 *>(a.ln2b + lE)[tid];
        e3sd = reinterpret_cast<const float2 *>(a.stated + lE)[tid];
        e3tk = reinterpret_cast<const float2 *>(a.tmk + lE)[tid];
        e3tr = reinterpret_cast<const float2 *>(a.tmr + lE)[tid];
        const float4 *vrow = reinterpret_cast<const float4 *>(a.vf + (lE + grow) * H);
        pw4[0] = vrow[bv];       pw4[1] = vrow[bv + 64];
        pw4[2] = vrow[bv + 128]; pw4[3] = vrow[bv + 192];
      }
      reinterpret_cast<float2 *>(s_a)[tid] = u2;
      lds_sync();
      float acc = dot4(pw2[0], s4a[b0h]) + dot4(pw2[1], s4a[b0h + 64]);
      acc = wred(acc);
      if (lane == 0) s_pp[wid] = acc;
      lds_sync();
      if (tid < 4) {
        float sxx = s_x[blk * 4 + tid] + s_pp[2 * tid] + s_pp[2 * tid + 1];
        cstoref(&ws_sxx[blk * 4 + tid], sxx);
      }
    }
    bar_arrive(a, ep, blk);
    { // t2: second half of vf
      const float4 *vrow = reinterpret_cast<const float4 *>(a.vf + (lE + grow) * H);
      pw4[4] = vrow[bv + 256]; pw4[5] = vrow[bv + 320];
      pw4[6] = vrow[bv + 384]; pw4[7] = vrow[bv + 448];
    }
    bar_spin(a, ep); ++ep;

    // ================= P3: LN2 + key_ffn + receptance_ffn =================
    {
      float2 vsx = cload2(ws_sxx + 2 * tid);
      // t1: next layer's P1 weights + elementwise (or final-LN vectors)
      if (l + 1 < L) {
        const size_t nE = (size_t)(l + 1) * E;
        const float4 *kr = reinterpret_cast<const float4 *>(a.ak + (nE + grow) * E);
        const float4 *vr = reinterpret_cast<const float4 *>(a.av + (nE + grow) * E);
        const float4 *rr4 = reinterpret_cast<const float4 *>(a.ar + (nE + grow) * E);
        pw1[0] = kr[b0h]; pw1[1] = kr[b0h + 64];
        pw1[2] = vr[b0h]; pw1[3] = vr[b0h + 64];
        pw1[4] = rr4[b0h]; pw1[5] = rr4[b0h + 64];
        e1w = reinterpret_cast<const float2 *>(a.ln1w + nE)[tid];
        e1b = reinterpret_cast<const float2 *>(a.ln1b + nE)[tid];
        e1sa = reinterpret_cast<const float2 *>(a.statea + nE)[tid];
        e1kk = reinterpret_cast<const float2 *>(a.kk + nE)[tid];
        e1vv = reinterpret_cast<const float2 *>(a.vv + nE)[tid];
        e1rr = reinterpret_cast<const float2 *>(a.rr + nE)[tid];
        if (tid < 4) {
          size_t o = nE + blk * 4 + tid;
          e_tf = a.tf[o]; e_td = a.td[o]; e_sb = a.stateb[o]; e_sc = a.statec[o];
        }
      } else {
        e1w = reinterpret_cast<const float2 *>(a.post0)[tid];
        e1b = reinterpret_cast<const float2 *>(a.post1)[tid];
      }
      float2 st = block_stats_v(vsx, s_x, s_red, tid, lane, wid);
      float2 xx = make_float2((vsx.x - st.x) * st.y * e3w.x + e3b.x,
                              (vsx.y - st.x) * st.y * e3w.y + e3b.y);
      reinterpret_cast<float2 *>(s_y)[tid] = xx;
      reinterpret_cast<float2 *>(s_a)[tid] =
          make_float2(xx.x + e3tk.x * e3sd.x, xx.y + e3tk.y * e3sd.y);
      reinterpret_cast<float2 *>(s_a + 1024)[tid] =
          make_float2(xx.x + e3tr.x * e3sd.x, xx.y + e3tr.y * e3sd.y);
      lds_sync();
      float k0 = dot4(pw3[0], s4a[lane]) + dot4(pw3[1], s4a[lane + 64]) +
                 dot4(pw3[2], s4a[lane + 128]) + dot4(pw3[3], s4a[lane + 192]);
      float k1 = dot4(pw3[4], s4a[lane]) + dot4(pw3[5], s4a[lane + 64]) +
                 dot4(pw3[6], s4a[lane + 128]) + dot4(pw3[7], s4a[lane + 192]);
      float ar_ = dot4(pw3[8], s4a[256 + b0h]) + dot4(pw3[9], s4a[256 + b0h + 64]);
      k0 = wred(k0); k1 = wred(k1); ar_ = wred(ar_);
      if (lane == 0) {
        float t0 = fmaxf(k0, 0.f), t1v = fmaxf(k1, 0.f);
        cstoref(&ws_km[blk * 16 + wid], t0 * t0);
        cstoref(&ws_km[blk * 16 + 8 + wid], t1v * t1v);
        s_pp[wid] = ar_;
      }
      lds_sync();
      if (tid < 4) {
        s_rt[tid] = expf(s_pp[2 * tid] + s_pp[2 * tid + 1]) + 1.0f;
        out_ddd[lE + blk * 4 + tid] = s_y[blk * 4 + tid];
      }
    }
    bar_arrive(a, ep, blk);
    bar_spin(a, ep); ++ep;

    // ================= P4: x_next = sxx + (vf @ km) / rt =================
    {
      float2 k0a = cload2(ws_km + 4 * tid);
      float2 k0b = cload2(ws_km + 4 * tid + 2);
      float2 k1a = cload2(ws_km + 2048 + 4 * tid);
      float2 k1b = cload2(ws_km + 2048 + 4 * tid + 2);
      reinterpret_cast<float2 *>(s_a)[2 * tid] = k0a;
      reinterpret_cast<float2 *>(s_a)[2 * tid + 1] = k0b;
      reinterpret_cast<float2 *>(s_a)[1024 + 2 * tid] = k1a;
      reinterpret_cast<float2 *>(s_a)[1024 + 2 * tid + 1] = k1b;
      lds_sync();
      float acc = dot4(pw4[0], s4a[bv]) + dot4(pw4[1], s4a[bv + 64]) +
                  dot4(pw4[2], s4a[bv + 128]) + dot4(pw4[3], s4a[bv + 192]) +
                  dot4(pw4[4], s4a[bv + 256]) + dot4(pw4[5], s4a[bv + 320]) +
                  dot4(pw4[6], s4a[bv + 384]) + dot4(pw4[7], s4a[bv + 448]);
      acc = wred(acc);
      if (lane == 0) s_pp[wid] = acc;
      lds_sync();
      if (tid < 4) {
        float xn = s_x[blk * 4 + tid] + (s_pp[2 * tid] + s_pp[2 * tid + 1]) / s_rt[tid];
        cstoref(&ws_x[blk * 4 + tid], xn);
      }
    }
    bar_arrive(a, ep, blk);
    bar_spin(a, ep); ++ep;
  }

  // ================= Final: LN + logits (double-buffered) =================
  {
    float2 v = cload2(ws_x + 2 * tid);
    float2 st = block_stats_v(v, s_x, s_red, tid, lane, wid);
    // e1w/e1b hold post0/post1 (prefetched during P3 of layer 11)
    reinterpret_cast<float2 *>(s_a)[tid] =
        make_float2((v.x - st.x) * st.y * e1w.x + e1b.x,
                    (v.y - st.x) * st.y * e1w.y + e1b.y);
    lds_sync();

    const float4 *P2 = reinterpret_cast<const float4 *>(a.post2);
    const int gw = blk * 8 + wid;  // 0..2047
    int r0 = gw, r1 = gw + 2048;
    float4 A0[4], A1[4];
    loadrow(A0, P2, r0, lane);
    loadrow(A1, P2, r1 < V ? r1 : r0, lane);
    while (true) {
      int n0 = r0 + 4096, n1 = n0 + 2048;
      bool more = n0 < V;
      float4 B0[4], B1[4];
      if (more) {
        loadrow(B0, P2, n0, lane);
        loadrow(B1, P2, n1 < V ? n1 : n0, lane);
      }
      float a0 = dot4(A0[0], s4a[lane]) + dot4(A0[1], s4a[lane + 64]) +
                 dot4(A0[2], s4a[lane + 128]) + dot4(A0[3], s4a[lane + 192]);
      float a1 = dot4(A1[0], s4a[lane]) + dot4(A1[1], s4a[lane + 64]) +
                 dot4(A1[2], s4a[lane + 128]) + dot4(A1[3], s4a[lane + 192]);
      a0 = wred(a0); a1 = wred(a1);
      if (lane == 0) {
        out_logits[r0] = a0;
        if (r1 < V) out_logits[r1] = a1;
      }
      if (!more) break;
#pragma unroll
      for (int q = 0; q < 4; ++q) { A0[q] = B0[q]; A1[q] = B1[q]; }
      r0 = n0; r1 = n1;
    }
  }
}

extern "C" void kernel_launch(void *const *d_in, const int *in_sizes, int n_in,
                              void *d_out, int out_size, void *d_ws, size_t ws_size,
                              hipStream_t stream) {
  (void)in_sizes; (void)n_in; (void)out_size; (void)ws_size;
  Args a;
  a.statea = (const float *)d_in[0];
  a.stateb = (const float *)d_in[1];
  a.statec = (const float *)d_in[2];
  a.stated = (const float *)d_in[3];
  a.pre    = (const float *)d_in[4];
  a.ln1w   = (const float *)d_in[5];
  a.ln1b   = (const float *)d_in[6];
  a.ln2w   = (const float *)d_in[7];
  a.ln2b   = (const float *)d_in[8];
  a.ak     = (const float *)d_in[9];
  a.ar     = (const float *)d_in[10];
  a.av     = (const float *)d_in[11];
  a.kk     = (const float *)d_in[12];
  a.vv     = (const float *)d_in[13];
  a.rr     = (const float *)d_in[14];
  a.tf     = (const float *)d_in[15];
  a.td     = (const float *)d_in[16];
  a.ovv    = (const float *)d_in[17];
  a.tmk    = (const float *)d_in[18];
  a.tmr    = (const float *)d_in[19];
  a.kf     = (const float *)d_in[20];
  a.rf     = (const float *)d_in[21];
  a.vf     = (const float *)d_in[22];
  a.post0  = (const float *)d_in[23];
  a.post1  = (const float *)d_in[24];
  a.post2  = (const float *)d_in[25];
  a.token  = (const int *)d_in[26];
  a.out    = (float *)d_out;

  a.flags  = (unsigned *)d_ws;                 // 256 flags, 128 B stride = 32 KB
  a.ws     = (float *)((char *)d_ws + 32768);  // coherent data vectors

  hipMemsetAsync(d_ws, 0, 32768, stream);
  rwkv_fused<<<NBLK, NTHR, 0, stream>>>(a);
}